// Round 12
// baseline (13426.582 us; speedup 1.0000x reference)
//
#include <hip/hip_runtime.h>
#include <cstdint>
#include <cstddef>

typedef short bf8v __attribute__((ext_vector_type(8)));   // 8 bf16 (4 VGPRs)
typedef float f4v  __attribute__((ext_vector_type(4)));   // 4 fp32 acc

#define NT 512
#define NB 64
#define NH 1024
#define NG 4096
#define BH (NB * NH)   // 65536
#define NBLK 256

__device__ __forceinline__ unsigned short f2bf(float f) {
    union { float f; unsigned int i; } v; v.f = f;
    unsigned int u = v.i;
    u += 0x7FFFu + ((u >> 16) & 1u);   // RNE
    return (unsigned short)(u >> 16);
}
__device__ __forceinline__ float gclamp(float x) { return fminf(30.0f, fmaxf(-30.0f, x)); }
__device__ __forceinline__ float sigm(float x)  { x = gclamp(x); return 1.0f / (1.0f + __expf(-x)); }
__device__ __forceinline__ float tanhx(float x) { x = gclamp(x); return 2.0f / (1.0f + __expf(-2.0f * x)) - 1.0f; }

__device__ __forceinline__ bf8v cvt8(const float4 f0, const float4 f1) {
    union { bf8v v; unsigned short s[8]; } u;
    u.s[0] = f2bf(f0.x); u.s[1] = f2bf(f0.y); u.s[2] = f2bf(f0.z); u.s[3] = f2bf(f0.w);
    u.s[4] = f2bf(f1.x); u.s[5] = f2bf(f1.y); u.s[6] = f2bf(f1.z); u.s[7] = f2bf(f1.w);
    return u.v;
}

// ---------------------------------------------------------------------------
__global__ __launch_bounds__(256)
void wconv_kernel(const float* __restrict__ src, unsigned short* __restrict__ dst)
{
    const size_t i = ((size_t)blockIdx.x * 256 + threadIdx.x) * 8;
    const float4 f0 = *reinterpret_cast<const float4*>(src + i);
    const float4 f1 = *reinterpret_cast<const float4*>(src + i + 4);
    const bf8v v = cvt8(f0, f1);
    *reinterpret_cast<uint4*>(dst + i) = *reinterpret_cast<const uint4*>(&v);
}

// ---------------------------------------------------------------------------
// Weight re-layout: Wperm[b][16][2048] bf16, pre-XOR-swizzled (see prior rounds).
// ---------------------------------------------------------------------------
__global__ __launch_bounds__(256)
void wperm_kernel(const float* __restrict__ Whh, const float* __restrict__ Wih,
                  unsigned short* __restrict__ Wp)
{
    const int t  = blockIdx.x * 256 + threadIdx.x;  // 0 .. 1048575
    const int k8 = t & 255;
    const int rf = t >> 8;                           // b*16 + r
    const int b  = rf >> 4;
    const int r  = rf & 15;
    const int wr = (r >> 2) * 1024 + b * 4 + (r & 3);
    const int k  = k8 * 8;
    const float* src = (k < 1024) ? (Whh + (size_t)wr * 1024 + k)
                                  : (Wih + (size_t)wr * 1024 + (k - 1024));
    const float4 f0 = *reinterpret_cast<const float4*>(src);
    const float4 f1 = *reinterpret_cast<const float4*>(src + 4);
    const bf8v v = cvt8(f0, f1);
    const int idx = (r * 2048 + k) ^ ((r & 7) << 3);
    *reinterpret_cast<uint4*>(Wp + (size_t)b * 32768 + idx) =
        *reinterpret_cast<const uint4*>(&v);
}

__global__ __launch_bounds__(256)
void init_kernel(const float* __restrict__ h0, const float* __restrict__ c0,
                 float* __restrict__ c_state, unsigned short* __restrict__ hb0)
{
    const int i = (blockIdx.x * 256 + threadIdx.x) * 4;
#pragma unroll
    for (int k = 0; k < 4; ++k) {
        c_state[i + k] = c0[i + k];
        hb0[i + k] = f2bf(h0[i + k]);
    }
}

// barrier region: 18 slots x 64B at ws+0: [0..15] sub-counters, [16] top, [17] flag
__global__ __launch_bounds__(64)
void bar_init_kernel(unsigned* __restrict__ bar)
{
    if (threadIdx.x < 18) bar[threadIdx.x * 16] = 0u;
}

// restore c_state head (clobbered by barrier region) for the fallback path
__global__ __launch_bounds__(512)
void fixup_kernel(const float* __restrict__ c0, float* __restrict__ c_state)
{
    c_state[threadIdx.x] = c0[threadIdx.x];
}

// ---------------------------------------------------------------------------
// PERSISTENT LSTM, custom grid barrier. 256 blocks x 512 thr, 1 block/CU
// (LDS padded > 80KB). Weights LDS-resident for all 512 steps.
// Per step: (a) x-waves (4-7) compute x-GEMM (independent of h!) while
// (b) lane 0 spins on the epoch flag (relaxed polls, one fence at exit);
// (c) h-waves (0-3) then compute h-GEMM; (d) pointwise, h write, arrive.
// Barrier: cumulative two-level counters (16 sub + top), monotonic epoch
// flag, no resets -> no race windows. Max skew 1 epoch by construction.
// ---------------------------------------------------------------------------
template<int XBF16>
__global__ __launch_bounds__(512, 1)
void lstm_persist2(const void* __restrict__ xt_base,
                   unsigned short* __restrict__ hb0,
                   unsigned short* __restrict__ hb1,
                   const unsigned short* __restrict__ Wp,
                   const float* __restrict__ bih,
                   const float* __restrict__ bhh,
                   const float* __restrict__ c0,
                   float* __restrict__ out,
                   unsigned* __restrict__ bar)
{
    __shared__ __align__(16) unsigned short Bs[16 * 2048]; // 64 KB
    __shared__ float gbuf[8][16][17];                      // 8.7 KB
    __shared__ unsigned char lds_pad[20480];               // force 1 block/CU

    const int tid  = threadIdx.x;
    const int wave = tid >> 6;
    const int lane = tid & 63;
    const int cl   = lane & 15;
    const int quad = lane >> 4;
    const int b    = blockIdx.x;
    const int rt   = wave & 3;
    const int kw   = wave >> 2;        // 0: h-half, 1: x-half
    if (gridDim.y == 7u) lds_pad[tid] = 1;   // never true; keeps pad alive

    // ---- stage 64 KB weight slab once ----
    {
        const unsigned short* gsrc = Wp + (size_t)b * 32768 + wave * 4096 + lane * 8;
#pragma unroll
        for (int i = 0; i < 8; ++i) {
            __builtin_amdgcn_global_load_lds(
                (const __attribute__((address_space(1))) unsigned int*)(gsrc + i * 512),
                (__attribute__((address_space(3))) unsigned int*)(Bs + wave * 4096 + i * 512),
                16, 0, 0);
        }
    }

    // ---- per-thread pointwise state ----
    float bsi = 0.f, bsf = 0.f, bsg = 0.f, bso = 0.f, creg = 0.f;
    size_t coff = 0;
    int ml = 0, rt2 = 0, hc = 0;
    if (tid < 256) {
        const int m = tid >> 2;
        hc  = tid & 3;
        ml  = m & 15;
        rt2 = m >> 4;
        const int col = b * 4 + hc;
        bsi = bih[col]          + bhh[col];
        bsf = bih[NH + col]     + bhh[NH + col];
        bsg = bih[2 * NH + col] + bhh[2 * NH + col];
        bso = bih[3 * NH + col] + bhh[3 * NH + col];
        coff = (size_t)m * NH + col;
        creg = c0[coff];
    }

    asm volatile("s_waitcnt vmcnt(0)" ::: "memory");
    __syncthreads();

    const int swz  = (cl & 7) << 3;
    const int bq   = quad * 8;
    const int arow = rt * 16 + cl;
    const unsigned short* Brow = Bs + cl * 2048 + kw * 1024;
    unsigned* const subp = bar + (b & 15) * 16;
    unsigned* const topp = bar + 16 * 16;
    unsigned* const flgp = bar + 17 * 16;

    for (int t = 0; t < NT; ++t) {
        const unsigned short* hp = (t & 1) ? hb1 : hb0;
        unsigned short*       hq = (t & 1) ? hb0 : hb1;

        // ---- (a) x-waves: x-GEMM, no dependence on h(t) ----
        if (kw == 1) {
            f4v a0 = {0.f, 0.f, 0.f, 0.f};
            f4v a1 = {0.f, 0.f, 0.f, 0.f};
            if (XBF16) {
                const unsigned short* Ap =
                    (const unsigned short*)xt_base + (size_t)t * BH + (size_t)arow * NH + bq;
#pragma unroll 8
                for (int kt = 0; kt < 32; ++kt) {
                    const bf8v a  = *reinterpret_cast<const bf8v*>(Ap + kt * 32);
                    const bf8v bb = *reinterpret_cast<const bf8v*>(Brow + ((kt * 32 + bq) ^ swz));
                    if (kt & 1) a1 = __builtin_amdgcn_mfma_f32_16x16x32_bf16(a, bb, a1, 0, 0, 0);
                    else        a0 = __builtin_amdgcn_mfma_f32_16x16x32_bf16(a, bb, a0, 0, 0, 0);
                }
            } else {
                const float* Ap =
                    (const float*)xt_base + (size_t)t * BH + (size_t)arow * NH + bq;
#pragma unroll 4
                for (int kt = 0; kt < 32; ++kt) {
                    const float4 f0 = *reinterpret_cast<const float4*>(Ap + kt * 32);
                    const float4 f1 = *reinterpret_cast<const float4*>(Ap + kt * 32 + 4);
                    const bf8v a  = cvt8(f0, f1);
                    const bf8v bb = *reinterpret_cast<const bf8v*>(Brow + ((kt * 32 + bq) ^ swz));
                    if (kt & 1) a1 = __builtin_amdgcn_mfma_f32_16x16x32_bf16(a, bb, a1, 0, 0, 0);
                    else        a0 = __builtin_amdgcn_mfma_f32_16x16x32_bf16(a, bb, a0, 0, 0, 0);
                }
            }
            const f4v accs = a0 + a1;
#pragma unroll
            for (int r = 0; r < 4; ++r)
                gbuf[wave][quad * 4 + r][cl] = accs[r];
        }

        // ---- (b) wait for h(t) visibility (epoch t); overlaps (a) ----
        if (t > 0 && tid == 0) {
            while (__hip_atomic_load(flgp, __ATOMIC_RELAXED, __HIP_MEMORY_SCOPE_AGENT)
                   < (unsigned)t)
                __builtin_amdgcn_s_sleep(1);
            __threadfence();   // one acquire-side fence per step
        }
        __syncthreads();

        // ---- (c) h-waves: h-GEMM ----
        if (kw == 0) {
            f4v a0 = {0.f, 0.f, 0.f, 0.f};
            f4v a1 = {0.f, 0.f, 0.f, 0.f};
            const unsigned short* Ap = hp + (size_t)arow * NH + bq;
#pragma unroll 8
            for (int kt = 0; kt < 32; ++kt) {
                const bf8v a  = *reinterpret_cast<const bf8v*>(Ap + kt * 32);
                const bf8v bb = *reinterpret_cast<const bf8v*>(Brow + ((kt * 32 + bq) ^ swz));
                if (kt & 1) a1 = __builtin_amdgcn_mfma_f32_16x16x32_bf16(a, bb, a1, 0, 0, 0);
                else        a0 = __builtin_amdgcn_mfma_f32_16x16x32_bf16(a, bb, a0, 0, 0, 0);
            }
            const f4v accs = a0 + a1;
#pragma unroll
            for (int r = 0; r < 4; ++r)
                gbuf[wave][quad * 4 + r][cl] = accs[r];
        }
        __syncthreads();

        // ---- (d) pointwise + h write ----
        if (tid < 256) {
            const float gi = gbuf[rt2][ml][hc]      + gbuf[4 + rt2][ml][hc]      + bsi;
            const float gf = gbuf[rt2][ml][4 + hc]  + gbuf[4 + rt2][ml][4 + hc]  + bsf;
            const float gg = gbuf[rt2][ml][8 + hc]  + gbuf[4 + rt2][ml][8 + hc]  + bsg;
            const float go = gbuf[rt2][ml][12 + hc] + gbuf[4 + rt2][ml][12 + hc] + bso;
            const float ig = sigm(gi);
            const float fg = sigm(gf);
            const float g2 = tanhx(gg);
            const float og = sigm(go);
            creg = fg * creg + ig * g2;
            const float hv = og * tanhx(creg);
            hq[coff] = f2bf(hv);
            out[(size_t)t * BH + coff] = hv;
        }
        __syncthreads();

        // ---- arrive (epoch t+1): cumulative two-level counters ----
        if (t < NT - 1 && tid == 0) {
            __threadfence();   // release h writes device-wide
            const unsigned e = (unsigned)(t + 1);
            const unsigned o = __hip_atomic_fetch_add(subp, 1u, __ATOMIC_ACQ_REL,
                                                      __HIP_MEMORY_SCOPE_AGENT);
            if (o == 16u * e - 1u) {
                const unsigned o2 = __hip_atomic_fetch_add(topp, 1u, __ATOMIC_ACQ_REL,
                                                           __HIP_MEMORY_SCOPE_AGENT);
                if (o2 == 16u * e - 1u)
                    __hip_atomic_store(flgp, e, __ATOMIC_RELEASE,
                                       __HIP_MEMORY_SCOPE_AGENT);
            }
        }
    }

    if (tid < 256) out[(size_t)NT * BH + coff] = creg;
}

// ---------------------------------------------------------------------------
// FALLBACK per-step kernel (round-6 proven, ~6.2 ms)
// ---------------------------------------------------------------------------
template<int XBF16>
__global__ __launch_bounds__(512)
void step_kernel(const void* __restrict__ xt_v,
                 const unsigned short* __restrict__ hp,
                 const unsigned short* __restrict__ Wp,
                 const float* __restrict__ bih,
                 const float* __restrict__ bhh,
                 float* __restrict__ c_state,
                 unsigned short* __restrict__ hn,
                 float* __restrict__ out_h,
                 float* __restrict__ out_c,
                 const int is_last)
{
    __shared__ __align__(16) unsigned short Bs[16 * 2048];
    __shared__ float gbuf[8][16][17];

    const int tid  = threadIdx.x;
    const int wave = tid >> 6;
    const int lane = tid & 63;
    const int cl   = lane & 15;
    const int quad = lane >> 4;
    const int b    = blockIdx.x;
    const int rt   = wave & 3;
    const int kw   = wave >> 2;

    {
        const unsigned short* gsrc = Wp + (size_t)b * 32768 + wave * 4096 + lane * 8;
#pragma unroll
        for (int i = 0; i < 8; ++i) {
            __builtin_amdgcn_global_load_lds(
                (const __attribute__((address_space(1))) unsigned int*)(gsrc + i * 512),
                (__attribute__((address_space(3))) unsigned int*)(Bs + wave * 4096 + i * 512),
                16, 0, 0);
        }
    }
    asm volatile("s_waitcnt vmcnt(0)" ::: "memory");
    __syncthreads();

    f4v a0 = {0.f, 0.f, 0.f, 0.f};
    f4v a1 = {0.f, 0.f, 0.f, 0.f};
    const int swz  = (cl & 7) << 3;
    const int bq   = quad * 8;
    const int arow = rt * 16 + cl;
    const unsigned short* Brow = Bs + cl * 2048 + kw * 1024;

    if (kw == 0) {
        const unsigned short* Ap = hp + (size_t)arow * NH + bq;
#pragma unroll 8
        for (int kt = 0; kt < 32; ++kt) {
            const bf8v a  = *reinterpret_cast<const bf8v*>(Ap + kt * 32);
            const bf8v bb = *reinterpret_cast<const bf8v*>(Brow + ((kt * 32 + bq) ^ swz));
            if (kt & 1) a1 = __builtin_amdgcn_mfma_f32_16x16x32_bf16(a, bb, a1, 0, 0, 0);
            else        a0 = __builtin_amdgcn_mfma_f32_16x16x32_bf16(a, bb, a0, 0, 0, 0);
        }
    } else if (XBF16) {
        const unsigned short* Ap = (const unsigned short*)xt_v + (size_t)arow * NH + bq;
#pragma unroll 8
        for (int kt = 0; kt < 32; ++kt) {
            const bf8v a  = *reinterpret_cast<const bf8v*>(Ap + kt * 32);
            const bf8v bb = *reinterpret_cast<const bf8v*>(Brow + ((kt * 32 + bq) ^ swz));
            if (kt & 1) a1 = __builtin_amdgcn_mfma_f32_16x16x32_bf16(a, bb, a1, 0, 0, 0);
            else        a0 = __builtin_amdgcn_mfma_f32_16x16x32_bf16(a, bb, a0, 0, 0, 0);
        }
    } else {
        const float* Ap = (const float*)xt_v + (size_t)arow * NH + bq;
#pragma unroll 4
        for (int kt = 0; kt < 32; ++kt) {
            const float4 f0 = *reinterpret_cast<const float4*>(Ap + kt * 32);
            const float4 f1 = *reinterpret_cast<const float4*>(Ap + kt * 32 + 4);
            const bf8v a  = cvt8(f0, f1);
            const bf8v bb = *reinterpret_cast<const bf8v*>(Brow + ((kt * 32 + bq) ^ swz));
            if (kt & 1) a1 = __builtin_amdgcn_mfma_f32_16x16x32_bf16(a, bb, a1, 0, 0, 0);
            else        a0 = __builtin_amdgcn_mfma_f32_16x16x32_bf16(a, bb, a0, 0, 0, 0);
        }
    }

    const f4v accs = a0 + a1;
#pragma unroll
    for (int r = 0; r < 4; ++r)
        gbuf[wave][quad * 4 + r][cl] = accs[r];
    __syncthreads();

    if (tid < 256) {
        const int m   = tid >> 2;
        const int hc  = tid & 3;
        const int ml  = m & 15;
        const int rt2 = m >> 4;
        const int col = b * 4 + hc;
        const float gi = gbuf[rt2][ml][hc]      + gbuf[4 + rt2][ml][hc]      + bih[col]          + bhh[col];
        const float gf = gbuf[rt2][ml][4 + hc]  + gbuf[4 + rt2][ml][4 + hc]  + bih[NH + col]     + bhh[NH + col];
        const float gg = gbuf[rt2][ml][8 + hc]  + gbuf[4 + rt2][ml][8 + hc]  + bih[2 * NH + col] + bhh[2 * NH + col];
        const float go = gbuf[rt2][ml][12 + hc] + gbuf[4 + rt2][ml][12 + hc] + bih[3 * NH + col] + bhh[3 * NH + col];
        const float ig = sigm(gi);
        const float fg = sigm(gf);
        const float g2 = tanhx(gg);
        const float og = sigm(go);
        const size_t off = (size_t)m * NH + col;
        const float cn = fg * c_state[off] + ig * g2;
        const float hv = og * tanhx(cn);
        c_state[off] = cn;
        hn[off] = f2bf(hv);
        out_h[off] = hv;
        if (is_last) out_c[off] = cn;
    }
}

extern "C" void kernel_launch(void* const* d_in, const int* in_sizes, int n_in,
                              void* d_out, int out_size, void* d_ws, size_t ws_size,
                              hipStream_t stream)
{
    (void)in_sizes; (void)n_in; (void)out_size;
    const float* X   = (const float*)d_in[0];
    const float* h0  = (const float*)d_in[1];
    const float* c0  = (const float*)d_in[2];
    const float* Wih = (const float*)d_in[3];
    const float* Whh = (const float*)d_in[4];
    const float* bih = (const float*)d_in[5];
    const float* bhh = (const float*)d_in[6];
    float* out = (float*)d_out;

    // ws layout (bytes) — mandatory footprint 17,301,504 B:
    //   c_state fp32[BH] @0 (262144)   [barrier region aliases first 1152 B
    //                                   in the persistent path]
    //   hb0 bf16[BH]     @262144 | hb1 @393216 | Wperm @524288 (16 MB)
    //   xb bf16[NT*BH]   @17301504 (67108864) [optional]
    char* ws = (char*)d_ws;
    float*          c_state = (float*)(ws);
    unsigned*       bar     = (unsigned*)(ws);
    unsigned short* hb0     = (unsigned short*)(ws + 262144);
    unsigned short* hb1     = (unsigned short*)(ws + 393216);
    unsigned short* Wperm   = (unsigned short*)(ws + 524288);
    unsigned short* xb      = (unsigned short*)(ws + 17301504);
    const int use_xb = (ws_size >= (size_t)17301504 + (size_t)67108864);

    wperm_kernel<<<4096, 256, 0, stream>>>(Whh, Wih, Wperm);
    init_kernel<<<64, 256, 0, stream>>>(h0, c0, c_state, hb0);
    if (use_xb)
        wconv_kernel<<<16384, 256, 0, stream>>>(X, xb);
    bar_init_kernel<<<1, 64, 0, stream>>>(bar);

    // ---- preferred: persistent kernel with custom grid barrier ----
    const void* xt = use_xb ? (const void*)xb : (const void*)X;
    const unsigned short* WpArg = Wperm;
    const float* bihArg = bih;
    const float* bhhArg = bhh;
    const float* c0Arg  = c0;
    float* outArg = out;
    unsigned short* h0Arg = hb0;
    unsigned short* h1Arg = hb1;
    unsigned* barArg = bar;
    void* args[] = {
        (void*)&xt, (void*)&h0Arg, (void*)&h1Arg, (void*)&WpArg,
        (void*)&bihArg, (void*)&bhhArg, (void*)&c0Arg, (void*)&outArg,
        (void*)&barArg
    };
    void* kfun = use_xb ? reinterpret_cast<void*>(&lstm_persist2<1>)
                        : reinterpret_cast<void*>(&lstm_persist2<0>);
    hipError_t e = hipLaunchCooperativeKernel(kfun, dim3(NBLK), dim3(512),
                                              args, 0, stream);
    if (e == hipSuccess) return;

    // ---- fallback: proven per-step loop (~6.2 ms) ----
    fixup_kernel<<<1, 512, 0, stream>>>(c0, c_state);
    for (int t = 0; t < NT; ++t) {
        const unsigned short* hp = (t & 1) ? hb1 : hb0;
        unsigned short*       hq = (t & 1) ? hb0 : hb1;
        float* out_h = out + (size_t)t * BH;
        float* out_c = out + (size_t)NT * BH;
        if (use_xb)
            step_kernel<1><<<256, 512, 0, stream>>>(
                xb + (size_t)t * BH, hp, Wperm, bih, bhh, c_state, hq,
                out_h, out_c, (t == NT - 1) ? 1 : 0);
        else
            step_kernel<0><<<256, 512, 0, stream>>>(
                X + (size_t)t * BH, hp, Wperm, bih, bhh, c_state, hq,
                out_h, out_c, (t == NT - 1) ? 1 : 0);
    }
}

// Round 13
// 9176.060 us; speedup vs baseline: 1.4632x; 1.4632x over previous
//
#include <hip/hip_runtime.h>
#include <cstdint>
#include <cstddef>

typedef short bf8v __attribute__((ext_vector_type(8)));   // 8 bf16 (4 VGPRs)
typedef float f4v  __attribute__((ext_vector_type(4)));   // 4 fp32 acc

#define NT 512
#define NB 64
#define NH 1024
#define NG 4096
#define BH (NB * NH)   // 65536

__device__ __forceinline__ unsigned short f2bf(float f) {
    union { float f; unsigned int i; } v; v.f = f;
    unsigned int u = v.i;
    u += 0x7FFFu + ((u >> 16) & 1u);   // RNE
    return (unsigned short)(u >> 16);
}
__device__ __forceinline__ float gclamp(float x) { return fminf(30.0f, fmaxf(-30.0f, x)); }
__device__ __forceinline__ float sigm(float x)  { x = gclamp(x); return 1.0f / (1.0f + __expf(-x)); }
__device__ __forceinline__ float tanhx(float x) { x = gclamp(x); return 2.0f / (1.0f + __expf(-2.0f * x)) - 1.0f; }

__device__ __forceinline__ bf8v cvt8(const float4 f0, const float4 f1) {
    union { bf8v v; unsigned short s[8]; } u;
    u.s[0] = f2bf(f0.x); u.s[1] = f2bf(f0.y); u.s[2] = f2bf(f0.z); u.s[3] = f2bf(f0.w);
    u.s[4] = f2bf(f1.x); u.s[5] = f2bf(f1.y); u.s[6] = f2bf(f1.z); u.s[7] = f2bf(f1.w);
    return u.v;
}

// ---------------------------------------------------------------------------
// fp32 -> bf16 conversion, 8 elems/thread (X precompute)
// ---------------------------------------------------------------------------
__global__ __launch_bounds__(256)
void wconv_kernel(const float* __restrict__ src, unsigned short* __restrict__ dst)
{
    const size_t i = ((size_t)blockIdx.x * 256 + threadIdx.x) * 8;
    const float4 f0 = *reinterpret_cast<const float4*>(src + i);
    const float4 f1 = *reinterpret_cast<const float4*>(src + i + 4);
    const bf8v v = cvt8(f0, f1);
    *reinterpret_cast<uint4*>(dst + i) = *reinterpret_cast<const uint4*>(&v);
}

// ---------------------------------------------------------------------------
// Weight re-layout: Wperm[b][16][2048] bf16, LINEAR (no swizzle — B is read
// from global/L2 in the step kernel, not from LDS).
//   block b owns H-cols b*4..b*4+3; tile row r = g*4+hc -> W row g*1024+b*4+hc
//   cols 0..1023 = Whh row, 1024..2047 = Wih row
// ---------------------------------------------------------------------------
__global__ __launch_bounds__(256)
void wperm_kernel(const float* __restrict__ Whh, const float* __restrict__ Wih,
                  unsigned short* __restrict__ Wp)
{
    const int t  = blockIdx.x * 256 + threadIdx.x;  // 0 .. 1048575
    const int k8 = t & 255;
    const int rf = t >> 8;                           // b*16 + r
    const int b  = rf >> 4;
    const int r  = rf & 15;
    const int wr = (r >> 2) * 1024 + b * 4 + (r & 3);
    const int k  = k8 * 8;
    const float* src = (k < 1024) ? (Whh + (size_t)wr * 1024 + k)
                                  : (Wih + (size_t)wr * 1024 + (k - 1024));
    const float4 f0 = *reinterpret_cast<const float4*>(src);
    const float4 f1 = *reinterpret_cast<const float4*>(src + 4);
    const bf8v v = cvt8(f0, f1);
    *reinterpret_cast<uint4*>(Wp + (size_t)b * 32768 + r * 2048 + k) =
        *reinterpret_cast<const uint4*>(&v);
}

// ---------------------------------------------------------------------------
// c_state = c0 (fp32 copy), hb0 = bf16(h0)
// ---------------------------------------------------------------------------
__global__ __launch_bounds__(256)
void init_kernel(const float* __restrict__ h0, const float* __restrict__ c0,
                 float* __restrict__ c_state, unsigned short* __restrict__ hb0)
{
    const int i = (blockIdx.x * 256 + threadIdx.x) * 4;
#pragma unroll
    for (int k = 0; k < 4; ++k) {
        c_state[i + k] = c0[i + k];
        hb0[i + k] = f2bf(h0[i + k]);
    }
}

// ---------------------------------------------------------------------------
// One LSTM timestep, SPLIT-K, NO LDS STAGING. grid 256 x 512 thr.
// Block b: 16 gate cols {g*1024+b*4+hc}. Waves 0-3: h-GEMM (K=1024, row-tile
// rt); waves 4-7: x-GEMM (K=1024). A and B fragments both read straight from
// global (L2-resident). No prologue stage, no vmcnt drain, no entry barrier,
// zero LDS bank conflicts. One barrier total (gbuf merge before pointwise).
// ---------------------------------------------------------------------------
template<int XBF16>
__global__ __launch_bounds__(512)
void step_kernel(const void* __restrict__ xt_v,
                 const unsigned short* __restrict__ hp,    // bf16 [64][1024]
                 const unsigned short* __restrict__ Wp,    // bf16 [256][16][2048]
                 const float* __restrict__ bih,
                 const float* __restrict__ bhh,
                 float* __restrict__ c_state,
                 unsigned short* __restrict__ hn,          // bf16 [64][1024]
                 float* __restrict__ out_h,
                 float* __restrict__ out_c,
                 const int is_last)
{
    __shared__ float gbuf[8][16][17];   // ~8.7 KB — only LDS in the kernel

    const int tid  = threadIdx.x;
    const int wave = tid >> 6;
    const int lane = tid & 63;
    const int cl   = lane & 15;
    const int quad = lane >> 4;
    const int b    = blockIdx.x;
    const int rt   = wave & 3;          // row-tile (batch rows rt*16..+15)
    const int kw   = wave >> 2;         // 0: h-half (K 0..1023), 1: x-half

    f4v a0 = {0.f, 0.f, 0.f, 0.f};
    f4v a1 = {0.f, 0.f, 0.f, 0.f};
    const int bq   = quad * 8;
    const int arow = rt * 16 + cl;
    // B fragment source: weight row cl of this block's 16, k = kw*1024 + kt*32 + bq
    const unsigned short* Bp = Wp + (size_t)b * 32768 + cl * 2048 + kw * 1024 + bq;

    if (kw == 0) {
        const unsigned short* Ap = hp + (size_t)arow * NH + bq;
#pragma unroll 8
        for (int kt = 0; kt < 32; ++kt) {
            const bf8v a  = *reinterpret_cast<const bf8v*>(Ap + kt * 32);
            const bf8v bb = *reinterpret_cast<const bf8v*>(Bp + kt * 32);
            if (kt & 1) a1 = __builtin_amdgcn_mfma_f32_16x16x32_bf16(a, bb, a1, 0, 0, 0);
            else        a0 = __builtin_amdgcn_mfma_f32_16x16x32_bf16(a, bb, a0, 0, 0, 0);
        }
    } else if (XBF16) {
        const unsigned short* Ap = (const unsigned short*)xt_v + (size_t)arow * NH + bq;
#pragma unroll 8
        for (int kt = 0; kt < 32; ++kt) {
            const bf8v a  = *reinterpret_cast<const bf8v*>(Ap + kt * 32);
            const bf8v bb = *reinterpret_cast<const bf8v*>(Bp + kt * 32);
            if (kt & 1) a1 = __builtin_amdgcn_mfma_f32_16x16x32_bf16(a, bb, a1, 0, 0, 0);
            else        a0 = __builtin_amdgcn_mfma_f32_16x16x32_bf16(a, bb, a0, 0, 0, 0);
        }
    } else {
        const float* Ap = (const float*)xt_v + (size_t)arow * NH + bq;
#pragma unroll 4
        for (int kt = 0; kt < 32; ++kt) {
            const float4 f0 = *reinterpret_cast<const float4*>(Ap + kt * 32);
            const float4 f1 = *reinterpret_cast<const float4*>(Ap + kt * 32 + 4);
            const bf8v a  = cvt8(f0, f1);
            const bf8v bb = *reinterpret_cast<const bf8v*>(Bp + kt * 32);
            if (kt & 1) a1 = __builtin_amdgcn_mfma_f32_16x16x32_bf16(a, bb, a1, 0, 0, 0);
            else        a0 = __builtin_amdgcn_mfma_f32_16x16x32_bf16(a, bb, a0, 0, 0, 0);
        }
    }

    // ---- merge partials: C/D layout col = lane&15, row = quad*4 + reg ----
    const f4v accs = a0 + a1;
#pragma unroll
    for (int r = 0; r < 4; ++r)
        gbuf[wave][quad * 4 + r][cl] = accs[r];
    __syncthreads();

    // pointwise: threads 0..255 own 1 cell each (m = tid>>2, hc = tid&3)
    if (tid < 256) {
        const int m   = tid >> 2;
        const int hc  = tid & 3;
        const int ml  = m & 15;
        const int rt2 = m >> 4;
        const int col = b * 4 + hc;
        const float gi = gbuf[rt2][ml][hc]      + gbuf[4 + rt2][ml][hc]      + bih[col]          + bhh[col];
        const float gf = gbuf[rt2][ml][4 + hc]  + gbuf[4 + rt2][ml][4 + hc]  + bih[NH + col]     + bhh[NH + col];
        const float gg = gbuf[rt2][ml][8 + hc]  + gbuf[4 + rt2][ml][8 + hc]  + bih[2 * NH + col] + bhh[2 * NH + col];
        const float go = gbuf[rt2][ml][12 + hc] + gbuf[4 + rt2][ml][12 + hc] + bih[3 * NH + col] + bhh[3 * NH + col];
        const float ig = sigm(gi);
        const float fg = sigm(gf);
        const float g2 = tanhx(gg);
        const float og = sigm(go);
        const size_t off = (size_t)m * NH + col;
        const float cn = fg * c_state[off] + ig * g2;
        const float hv = og * tanhx(cn);
        c_state[off] = cn;
        hn[off] = f2bf(hv);
        out_h[off] = hv;
        if (is_last) out_c[off] = cn;
    }
}

extern "C" void kernel_launch(void* const* d_in, const int* in_sizes, int n_in,
                              void* d_out, int out_size, void* d_ws, size_t ws_size,
                              hipStream_t stream)
{
    (void)in_sizes; (void)n_in; (void)out_size;
    const float* X   = (const float*)d_in[0];
    const float* h0  = (const float*)d_in[1];
    const float* c0  = (const float*)d_in[2];
    const float* Wih = (const float*)d_in[3];
    const float* Whh = (const float*)d_in[4];
    const float* bih = (const float*)d_in[5];
    const float* bhh = (const float*)d_in[6];
    float* out = (float*)d_out;

    // ws layout (bytes) — mandatory footprint 17,301,504 B:
    //   c_state fp32[BH]            @ 0        (262144)
    //   hb0     bf16[BH]            @ 262144   (131072)
    //   hb1     bf16[BH]            @ 393216   (131072)
    //   Wperm   bf16[256][32768]    @ 524288   (16777216)
    //   xb      bf16[NT*BH]         @ 17301504 (67108864)  [optional]
    char* ws = (char*)d_ws;
    float*          c_state = (float*)(ws);
    unsigned short* hb0     = (unsigned short*)(ws + 262144);
    unsigned short* hb1     = (unsigned short*)(ws + 393216);
    unsigned short* Wperm   = (unsigned short*)(ws + 524288);
    unsigned short* xb      = (unsigned short*)(ws + 17301504);
    const int use_xb = (ws_size >= (size_t)17301504 + (size_t)67108864);

    wperm_kernel<<<4096, 256, 0, stream>>>(Whh, Wih, Wperm);
    init_kernel<<<64, 256, 0, stream>>>(h0, c0, c_state, hb0);
    if (use_xb)
        wconv_kernel<<<16384, 256, 0, stream>>>(X, xb);

    for (int t = 0; t < NT; ++t) {
        const unsigned short* hp = (t & 1) ? hb1 : hb0;
        unsigned short*       hq = (t & 1) ? hb0 : hb1;
        float* out_h = out + (size_t)t * BH;
        float* out_c = out + (size_t)NT * BH;
        if (use_xb)
            step_kernel<1><<<256, 512, 0, stream>>>(
                xb + (size_t)t * BH, hp, Wperm, bih, bhh, c_state, hq,
                out_h, out_c, (t == NT - 1) ? 1 : 0);
        else
            step_kernel<0><<<256, 512, 0, stream>>>(
                X + (size_t)t * BH, hp, Wperm, bih, bhh, c_state, hq,
                out_h, out_c, (t == NT - 1) ? 1 : 0);
    }
}

// Round 15
// 4801.843 us; speedup vs baseline: 2.7961x; 1.9109x over previous
//
#include <hip/hip_runtime.h>
#include <cstdint>
#include <cstddef>

typedef short bf8v __attribute__((ext_vector_type(8)));   // 8 bf16 (4 VGPRs)
typedef float f4v  __attribute__((ext_vector_type(4)));   // 4 fp32 acc

#define NT 512
#define NB 64
#define NH 1024
#define NG 4096
#define BH (NB * NH)   // 65536
#define NBLK 256

__device__ __forceinline__ unsigned short f2bf(float f) {
    union { float f; unsigned int i; } v; v.f = f;
    unsigned int u = v.i;
    u += 0x7FFFu + ((u >> 16) & 1u);   // RNE
    return (unsigned short)(u >> 16);
}
__device__ __forceinline__ float gclamp(float x) { return fminf(30.0f, fmaxf(-30.0f, x)); }
__device__ __forceinline__ float sigm(float x)  { x = gclamp(x); return 1.0f / (1.0f + __expf(-x)); }
__device__ __forceinline__ float tanhx(float x) { x = gclamp(x); return 2.0f / (1.0f + __expf(-2.0f * x)) - 1.0f; }

__device__ __forceinline__ bf8v cvt8(const float4 f0, const float4 f1) {
    union { bf8v v; unsigned short s[8]; } u;
    u.s[0] = f2bf(f0.x); u.s[1] = f2bf(f0.y); u.s[2] = f2bf(f0.z); u.s[3] = f2bf(f0.w);
    u.s[4] = f2bf(f1.x); u.s[5] = f2bf(f1.y); u.s[6] = f2bf(f1.z); u.s[7] = f2bf(f1.w);
    return u.v;
}

// device-coherent 16B load (bypass L1/L2, read at coherence point)
#define LD16DC(dst, base, IMM)                                              \
    asm volatile("global_load_dwordx4 %0, %1, off offset:%2 sc0 sc1"        \
                 : "=v"(dst) : "v"(base), "i"(IMM))

#define LDB16(A, P, OFS)                                                    \
    LD16DC(A[0],  P, (OFS) + 0);    LD16DC(A[1],  P, (OFS) + 64);           \
    LD16DC(A[2],  P, (OFS) + 128);  LD16DC(A[3],  P, (OFS) + 192);          \
    LD16DC(A[4],  P, (OFS) + 256);  LD16DC(A[5],  P, (OFS) + 320);          \
    LD16DC(A[6],  P, (OFS) + 384);  LD16DC(A[7],  P, (OFS) + 448);          \
    LD16DC(A[8],  P, (OFS) + 512);  LD16DC(A[9],  P, (OFS) + 576);          \
    LD16DC(A[10], P, (OFS) + 640);  LD16DC(A[11], P, (OFS) + 704);          \
    LD16DC(A[12], P, (OFS) + 768);  LD16DC(A[13], P, (OFS) + 832);          \
    LD16DC(A[14], P, (OFS) + 896);  LD16DC(A[15], P, (OFS) + 960)

__device__ __forceinline__ void st2_dc(void* p, unsigned v) {
    asm volatile("global_store_short %0, %1, off sc0 sc1"
                 :: "v"(p), "v"(v) : "memory");
}

// ---------------------------------------------------------------------------
__global__ __launch_bounds__(256)
void wconv_kernel(const float* __restrict__ src, unsigned short* __restrict__ dst)
{
    const size_t i = ((size_t)blockIdx.x * 256 + threadIdx.x) * 8;
    const float4 f0 = *reinterpret_cast<const float4*>(src + i);
    const float4 f1 = *reinterpret_cast<const float4*>(src + i + 4);
    const bf8v v = cvt8(f0, f1);
    *reinterpret_cast<uint4*>(dst + i) = *reinterpret_cast<const uint4*>(&v);
}

// ---------------------------------------------------------------------------
// Weight re-layout: Wperm[b][16][2048] bf16, pre-XOR-swizzled (round-6 proven).
// ---------------------------------------------------------------------------
__global__ __launch_bounds__(256)
void wperm_kernel(const float* __restrict__ Whh, const float* __restrict__ Wih,
                  unsigned short* __restrict__ Wp)
{
    const int t  = blockIdx.x * 256 + threadIdx.x;  // 0 .. 1048575
    const int k8 = t & 255;
    const int rf = t >> 8;                           // b*16 + r
    const int b  = rf >> 4;
    const int r  = rf & 15;
    const int wr = (r >> 2) * 1024 + b * 4 + (r & 3);
    const int k  = k8 * 8;
    const float* src = (k < 1024) ? (Whh + (size_t)wr * 1024 + k)
                                  : (Wih + (size_t)wr * 1024 + (k - 1024));
    const float4 f0 = *reinterpret_cast<const float4*>(src);
    const float4 f1 = *reinterpret_cast<const float4*>(src + 4);
    const bf8v v = cvt8(f0, f1);
    const int idx = (r * 2048 + k) ^ ((r & 7) << 3);
    *reinterpret_cast<uint4*>(Wp + (size_t)b * 32768 + idx) =
        *reinterpret_cast<const uint4*>(&v);
}

__global__ __launch_bounds__(256)
void init_kernel(const float* __restrict__ h0, const float* __restrict__ c0,
                 float* __restrict__ c_state, unsigned short* __restrict__ hb0)
{
    const int i = (blockIdx.x * 256 + threadIdx.x) * 4;
#pragma unroll
    for (int k = 0; k < 4; ++k) {
        c_state[i + k] = c0[i + k];
        hb0[i + k] = f2bf(h0[i + k]);
    }
}

// barrier region: 18 slots x 64B at ws+0
__global__ __launch_bounds__(64)
void bar_init_kernel(unsigned* __restrict__ bar)
{
    if (threadIdx.x < 18) bar[threadIdx.x * 16] = 0u;
}

__global__ __launch_bounds__(512)
void fixup_kernel(const float* __restrict__ c0, float* __restrict__ c_state)
{
    c_state[threadIdx.x] = c0[threadIdx.x];
}

// ---------------------------------------------------------------------------
// PERSISTENT LSTM v3 — FENCE-FREE. 256 blocks x 512 thr. Weights in LDS
// (staged once); c in registers; h exchanged via sc0/sc1 device-coherent
// loads/stores (bypass L2 -> no cache maintenance anywhere); barrier = pure
// RELAXED agent-scope atomics, ordering by per-wave s_waitcnt vmcnt(0)
// before arrive. x-waves (4-7) overlap the flag spin.
// ---------------------------------------------------------------------------
template<int XBF16>
__global__ __launch_bounds__(512, 1)
void lstm_persist3(const void* __restrict__ xt_base,
                   unsigned short* __restrict__ hb0,
                   unsigned short* __restrict__ hb1,
                   const unsigned short* __restrict__ Wp,
                   const float* __restrict__ bih,
                   const float* __restrict__ bhh,
                   const float* __restrict__ c0,
                   float* __restrict__ out,
                   unsigned* __restrict__ bar)
{
    __shared__ __align__(16) unsigned short Bs[16 * 2048]; // 64 KB
    __shared__ float gbuf[8][16][17];                      // 8.7 KB

    const int tid  = threadIdx.x;
    const int wave = tid >> 6;
    const int lane = tid & 63;
    const int cl   = lane & 15;
    const int quad = lane >> 4;
    const int b    = blockIdx.x;
    const int rt   = wave & 3;
    const int kw   = wave >> 2;        // 0: h-half, 1: x-half

    {   // stage weights once
        const unsigned short* gsrc = Wp + (size_t)b * 32768 + wave * 4096 + lane * 8;
#pragma unroll
        for (int i = 0; i < 8; ++i) {
            __builtin_amdgcn_global_load_lds(
                (const __attribute__((address_space(1))) unsigned int*)(gsrc + i * 512),
                (__attribute__((address_space(3))) unsigned int*)(Bs + wave * 4096 + i * 512),
                16, 0, 0);
        }
    }

    float bsi = 0.f, bsf = 0.f, bsg = 0.f, bso = 0.f, creg = 0.f;
    size_t coff = 0;
    int ml = 0, rt2 = 0, hc = 0;
    if (tid < 256) {
        const int m = tid >> 2;
        hc  = tid & 3;
        ml  = m & 15;
        rt2 = m >> 4;
        const int col = b * 4 + hc;
        bsi = bih[col]          + bhh[col];
        bsf = bih[NH + col]     + bhh[NH + col];
        bsg = bih[2 * NH + col] + bhh[2 * NH + col];
        bso = bih[3 * NH + col] + bhh[3 * NH + col];
        coff = (size_t)m * NH + col;
        creg = c0[coff];
    }

    asm volatile("s_waitcnt vmcnt(0)" ::: "memory");
    __syncthreads();

    const int swz  = (cl & 7) << 3;
    const int bq   = quad * 8;
    const int arow = rt * 16 + cl;
    const unsigned short* Brow = Bs + cl * 2048 + kw * 1024;
    unsigned* const subp = bar + (b & 15) * 16;
    unsigned* const topp = bar + 16 * 16;
    unsigned* const flgp = bar + 17 * 16;

    for (int t = 0; t < NT; ++t) {
        const unsigned short* hp = (t & 1) ? hb1 : hb0;
        unsigned short*       hq = (t & 1) ? hb0 : hb1;

        // ---- (a) x-waves: x-GEMM (normal cached loads; overlaps spin) ----
        if (kw == 1) {
            f4v a0 = {0.f, 0.f, 0.f, 0.f};
            f4v a1 = {0.f, 0.f, 0.f, 0.f};
            if (XBF16) {
                const unsigned short* Ap =
                    (const unsigned short*)xt_base + (size_t)t * BH + (size_t)arow * NH + bq;
#pragma unroll 8
                for (int kt = 0; kt < 32; ++kt) {
                    const bf8v a  = *reinterpret_cast<const bf8v*>(Ap + kt * 32);
                    const bf8v bb = *reinterpret_cast<const bf8v*>(Brow + ((kt * 32 + bq) ^ swz));
                    if (kt & 1) a1 = __builtin_amdgcn_mfma_f32_16x16x32_bf16(a, bb, a1, 0, 0, 0);
                    else        a0 = __builtin_amdgcn_mfma_f32_16x16x32_bf16(a, bb, a0, 0, 0, 0);
                }
            } else {
                const float* Ap =
                    (const float*)xt_base + (size_t)t * BH + (size_t)arow * NH + bq;
#pragma unroll 4
                for (int kt = 0; kt < 32; ++kt) {
                    const float4 f0 = *reinterpret_cast<const float4*>(Ap + kt * 32);
                    const float4 f1 = *reinterpret_cast<const float4*>(Ap + kt * 32 + 4);
                    const bf8v a  = cvt8(f0, f1);
                    const bf8v bb = *reinterpret_cast<const bf8v*>(Brow + ((kt * 32 + bq) ^ swz));
                    if (kt & 1) a1 = __builtin_amdgcn_mfma_f32_16x16x32_bf16(a, bb, a1, 0, 0, 0);
                    else        a0 = __builtin_amdgcn_mfma_f32_16x16x32_bf16(a, bb, a0, 0, 0, 0);
                }
            }
            const f4v accs = a0 + a1;
#pragma unroll
            for (int r = 0; r < 4; ++r)
                gbuf[wave][quad * 4 + r][cl] = accs[r];
        }

        // ---- (b) wait for epoch t (pure relaxed poll, no fences) ----
        if (t > 0 && tid == 0) {
            while (__hip_atomic_load(flgp, __ATOMIC_RELAXED, __HIP_MEMORY_SCOPE_AGENT)
                   < (unsigned)t)
                __builtin_amdgcn_s_sleep(8);
        }
        __syncthreads();

        // ---- (c) h-waves: h-GEMM, device-coherent A loads, 2x16 batches ----
        if (kw == 0) {
            f4v a0 = {0.f, 0.f, 0.f, 0.f};
            f4v a1 = {0.f, 0.f, 0.f, 0.f};
            const unsigned short* Ap = hp + (size_t)arow * NH + bq;
            bf8v ah[16];
            LDB16(ah, Ap, 0);
            asm volatile("s_waitcnt vmcnt(0)" ::: "memory");
            __builtin_amdgcn_sched_barrier(0);
#pragma unroll
            for (int kt = 0; kt < 16; ++kt) {
                const bf8v bb = *reinterpret_cast<const bf8v*>(Brow + ((kt * 32 + bq) ^ swz));
                if (kt & 1) a1 = __builtin_amdgcn_mfma_f32_16x16x32_bf16(ah[kt], bb, a1, 0, 0, 0);
                else        a0 = __builtin_amdgcn_mfma_f32_16x16x32_bf16(ah[kt], bb, a0, 0, 0, 0);
            }
            LDB16(ah, Ap, 1024);
            asm volatile("s_waitcnt vmcnt(0)" ::: "memory");
            __builtin_amdgcn_sched_barrier(0);
#pragma unroll
            for (int kt = 16; kt < 32; ++kt) {
                const bf8v bb = *reinterpret_cast<const bf8v*>(Brow + ((kt * 32 + bq) ^ swz));
                if (kt & 1) a1 = __builtin_amdgcn_mfma_f32_16x16x32_bf16(ah[kt - 16], bb, a1, 0, 0, 0);
                else        a0 = __builtin_amdgcn_mfma_f32_16x16x32_bf16(ah[kt - 16], bb, a0, 0, 0, 0);
            }
            const f4v accs = a0 + a1;
#pragma unroll
            for (int r = 0; r < 4; ++r)
                gbuf[wave][quad * 4 + r][cl] = accs[r];
        }
        __syncthreads();

        // ---- (d) pointwise; h write-through to coherence point ----
        if (tid < 256) {
            const float gi = gbuf[rt2][ml][hc]      + gbuf[4 + rt2][ml][hc]      + bsi;
            const float gf = gbuf[rt2][ml][4 + hc]  + gbuf[4 + rt2][ml][4 + hc]  + bsf;
            const float gg = gbuf[rt2][ml][8 + hc]  + gbuf[4 + rt2][ml][8 + hc]  + bsg;
            const float go = gbuf[rt2][ml][12 + hc] + gbuf[4 + rt2][ml][12 + hc] + bso;
            const float ig = sigm(gi);
            const float fg = sigm(gf);
            const float g2 = tanhx(gg);
            const float og = sigm(go);
            creg = fg * creg + ig * g2;
            const float hv = og * tanhx(creg);
            st2_dc(hq + coff, (unsigned)f2bf(hv));
            out[(size_t)t * BH + coff] = hv;
        }
        asm volatile("s_waitcnt vmcnt(0)" ::: "memory");  // per-wave: h at L3
        __syncthreads();

        // ---- arrive (epoch t+1): pure relaxed cumulative counters ----
        if (t < NT - 1 && tid == 0) {
            const unsigned e = (unsigned)(t + 1);
            const unsigned o = __hip_atomic_fetch_add(subp, 1u, __ATOMIC_RELAXED,
                                                      __HIP_MEMORY_SCOPE_AGENT);
            if (o == 16u * e - 1u) {
                const unsigned o2 = __hip_atomic_fetch_add(topp, 1u, __ATOMIC_RELAXED,
                                                           __HIP_MEMORY_SCOPE_AGENT);
                if (o2 == 16u * e - 1u)
                    __hip_atomic_store(flgp, e, __ATOMIC_RELAXED,
                                       __HIP_MEMORY_SCOPE_AGENT);
            }
        }
    }

    if (tid < 256) out[(size_t)NT * BH + coff] = creg;
}

// ---------------------------------------------------------------------------
// FALLBACK per-step kernel (round-6 proven, ~6.2 ms)
// ---------------------------------------------------------------------------
template<int XBF16>
__global__ __launch_bounds__(512)
void step_kernel(const void* __restrict__ xt_v,
                 const unsigned short* __restrict__ hp,
                 const unsigned short* __restrict__ Wp,
                 const float* __restrict__ bih,
                 const float* __restrict__ bhh,
                 float* __restrict__ c_state,
                 unsigned short* __restrict__ hn,
                 float* __restrict__ out_h,
                 float* __restrict__ out_c,
                 const int is_last)
{
    __shared__ __align__(16) unsigned short Bs[16 * 2048];
    __shared__ float gbuf[8][16][17];

    const int tid  = threadIdx.x;
    const int wave = tid >> 6;
    const int lane = tid & 63;
    const int cl   = lane & 15;
    const int quad = lane >> 4;
    const int b    = blockIdx.x;
    const int rt   = wave & 3;
    const int kw   = wave >> 2;

    {
        const unsigned short* gsrc = Wp + (size_t)b * 32768 + wave * 4096 + lane * 8;
#pragma unroll
        for (int i = 0; i < 8; ++i) {
            __builtin_amdgcn_global_load_lds(
                (const __attribute__((address_space(1))) unsigned int*)(gsrc + i * 512),
                (__attribute__((address_space(3))) unsigned int*)(Bs + wave * 4096 + i * 512),
                16, 0, 0);
        }
    }
    asm volatile("s_waitcnt vmcnt(0)" ::: "memory");
    __syncthreads();

    f4v a0 = {0.f, 0.f, 0.f, 0.f};
    f4v a1 = {0.f, 0.f, 0.f, 0.f};
    const int swz  = (cl & 7) << 3;
    const int bq   = quad * 8;
    const int arow = rt * 16 + cl;
    const unsigned short* Brow = Bs + cl * 2048 + kw * 1024;

    if (kw == 0) {
        const unsigned short* Ap = hp + (size_t)arow * NH + bq;
#pragma unroll 8
        for (int kt = 0; kt < 32; ++kt) {
            const bf8v a  = *reinterpret_cast<const bf8v*>(Ap + kt * 32);
            const bf8v bb = *reinterpret_cast<const bf8v*>(Brow + ((kt * 32 + bq) ^ swz));
            if (kt & 1) a1 = __builtin_amdgcn_mfma_f32_16x16x32_bf16(a, bb, a1, 0, 0, 0);
            else        a0 = __builtin_amdgcn_mfma_f32_16x16x32_bf16(a, bb, a0, 0, 0, 0);
        }
    } else if (XBF16) {
        const unsigned short* Ap = (const unsigned short*)xt_v + (size_t)arow * NH + bq;
#pragma unroll 8
        for (int kt = 0; kt < 32; ++kt) {
            const bf8v a  = *reinterpret_cast<const bf8v*>(Ap + kt * 32);
            const bf8v bb = *reinterpret_cast<const bf8v*>(Brow + ((kt * 32 + bq) ^ swz));
            if (kt & 1) a1 = __builtin_amdgcn_mfma_f32_16x16x32_bf16(a, bb, a1, 0, 0, 0);
            else        a0 = __builtin_amdgcn_mfma_f32_16x16x32_bf16(a, bb, a0, 0, 0, 0);
        }
    } else {
        const float* Ap = (const float*)xt_v + (size_t)arow * NH + bq;
#pragma unroll 4
        for (int kt = 0; kt < 32; ++kt) {
            const float4 f0 = *reinterpret_cast<const float4*>(Ap + kt * 32);
            const float4 f1 = *reinterpret_cast<const float4*>(Ap + kt * 32 + 4);
            const bf8v a  = cvt8(f0, f1);
            const bf8v bb = *reinterpret_cast<const bf8v*>(Brow + ((kt * 32 + bq) ^ swz));
            if (kt & 1) a1 = __builtin_amdgcn_mfma_f32_16x16x32_bf16(a, bb, a1, 0, 0, 0);
            else        a0 = __builtin_amdgcn_mfma_f32_16x16x32_bf16(a, bb, a0, 0, 0, 0);
        }
    }

    const f4v accs = a0 + a1;
#pragma unroll
    for (int r = 0; r < 4; ++r)
        gbuf[wave][quad * 4 + r][cl] = accs[r];
    __syncthreads();

    if (tid < 256) {
        const int m   = tid >> 2;
        const int hc  = tid & 3;
        const int ml  = m & 15;
        const int rt2 = m >> 4;
        const int col = b * 4 + hc;
        const float gi = gbuf[rt2][ml][hc]      + gbuf[4 + rt2][ml][hc]      + bih[col]          + bhh[col];
        const float gf = gbuf[rt2][ml][4 + hc]  + gbuf[4 + rt2][ml][4 + hc]  + bih[NH + col]     + bhh[NH + col];
        const float gg = gbuf[rt2][ml][8 + hc]  + gbuf[4 + rt2][ml][8 + hc]  + bih[2 * NH + col] + bhh[2 * NH + col];
        const float go = gbuf[rt2][ml][12 + hc] + gbuf[4 + rt2][ml][12 + hc] + bih[3 * NH + col] + bhh[3 * NH + col];
        const float ig = sigm(gi);
        const float fg = sigm(gf);
        const float g2 = tanhx(gg);
        const float og = sigm(go);
        const size_t off = (size_t)m * NH + col;
        const float cn = fg * c_state[off] + ig * g2;
        const float hv = og * tanhx(cn);
        c_state[off] = cn;
        hn[off] = f2bf(hv);
        out_h[off] = hv;
        if (is_last) out_c[off] = cn;
    }
}

extern "C" void kernel_launch(void* const* d_in, const int* in_sizes, int n_in,
                              void* d_out, int out_size, void* d_ws, size_t ws_size,
                              hipStream_t stream)
{
    (void)in_sizes; (void)n_in; (void)out_size;
    const float* X   = (const float*)d_in[0];
    const float* h0  = (const float*)d_in[1];
    const float* c0  = (const float*)d_in[2];
    const float* Wih = (const float*)d_in[3];
    const float* Whh = (const float*)d_in[4];
    const float* bih = (const float*)d_in[5];
    const float* bhh = (const float*)d_in[6];
    float* out = (float*)d_out;

    // ws layout — mandatory 17,301,504 B:
    //   c_state fp32[BH] @0 (bar region aliases head; fixup for fallback)
    //   hb0 @262144 | hb1 @393216 | Wperm @524288 (16 MB) | xb @17301504 [opt]
    char* ws = (char*)d_ws;
    float*          c_state = (float*)(ws);
    unsigned*       bar     = (unsigned*)(ws);
    unsigned short* hb0     = (unsigned short*)(ws + 262144);
    unsigned short* hb1     = (unsigned short*)(ws + 393216);
    unsigned short* Wperm   = (unsigned short*)(ws + 524288);
    unsigned short* xb      = (unsigned short*)(ws + 17301504);
    const int use_xb = (ws_size >= (size_t)17301504 + (size_t)67108864);

    wperm_kernel<<<4096, 256, 0, stream>>>(Whh, Wih, Wperm);
    init_kernel<<<64, 256, 0, stream>>>(h0, c0, c_state, hb0);
    if (use_xb)
        wconv_kernel<<<16384, 256, 0, stream>>>(X, xb);
    bar_init_kernel<<<1, 64, 0, stream>>>(bar);

    const void* xt = use_xb ? (const void*)xb : (const void*)X;
    const unsigned short* WpArg = Wperm;
    const float* bihArg = bih;
    const float* bhhArg = bhh;
    const float* c0Arg  = c0;
    float* outArg = out;
    unsigned short* h0Arg = hb0;
    unsigned short* h1Arg = hb1;
    unsigned* barArg = bar;
    void* args[] = {
        (void*)&xt, (void*)&h0Arg, (void*)&h1Arg, (void*)&WpArg,
        (void*)&bihArg, (void*)&bhhArg, (void*)&c0Arg, (void*)&outArg,
        (void*)&barArg
    };
    void* kfun = use_xb ? reinterpret_cast<void*>(&lstm_persist3<1>)
                        : reinterpret_cast<void*>(&lstm_persist3<0>);
    hipError_t e = hipLaunchCooperativeKernel(kfun, dim3(NBLK), dim3(512),
                                              args, 0, stream);
    if (e == hipSuccess) return;

    // fallback: proven per-step loop (~6.2 ms)
    fixup_kernel<<<1, 512, 0, stream>>>(c0, c_state);
    for (int t = 0; t < NT; ++t) {
        const unsigned short* hp = (t & 1) ? hb1 : hb0;
        unsigned short*       hq = (t & 1) ? hb0 : hb1;
        float* out_h = out + (size_t)t * BH;
        float* out_c = out + (size_t)NT * BH;
        if (use_xb)
            step_kernel<1><<<256, 512, 0, stream>>>(
                xb + (size_t)t * BH, hp, Wperm, bih, bhh, c_state, hq,
                out_h, out_c, (t == NT - 1) ? 1 : 0);
        else
            step_kernel<0><<<256, 512, 0, stream>>>(
                X + (size_t)t * BH, hp, Wperm, bih, bhh, c_state, hq,
                out_h, out_c, (t == NT - 1) ? 1 : 0);
    }
}